// Round 2
// baseline (923.291 us; speedup 1.0000x reference)
//
#include <hip/hip_runtime.h>

// Problem constants
#define BB 32
#define CC 256
#define HWIMG 4096          // 64*64
#define NPIX 131072         // 32*4096
#define KCODES 1024
#define MAXFLAG 65536
#define MARGIN 0.015625f    // 1/64 safety margin for fp32 distance error

// ---------------- Kernel A: transpose codebook + e_sq + zero flag counter ----
__global__ __launch_bounds__(256) void prep_kernel(
    const float* __restrict__ cb, float* __restrict__ eT,
    float* __restrict__ esq, int* __restrict__ flag_cnt)
{
    int k = blockIdx.x;          // 0..1023
    int c = threadIdx.x;         // 0..255
    float v = cb[(size_t)k * CC + c];
    eT[(size_t)c * KCODES + k] = v;
    float s = v * v;
    #pragma unroll
    for (int m = 32; m; m >>= 1) s += __shfl_xor(s, m, 64);
    __shared__ float red[4];
    if ((threadIdx.x & 63) == 0) red[threadIdx.x >> 6] = s;
    __syncthreads();
    if (threadIdx.x == 0) {
        esq[k] = (red[0] + red[1]) + (red[2] + red[3]);
        if (k == 0) *flag_cnt = 0;
    }
}

// ---------------- Kernel B: fp32 distance + running argmin with margin flag --
// Block: 256 threads. Tile: 64 pixels x 256 codes per k-pass (4 passes).
// Micro-tile per thread: 8 pixels x 8 codes (64 fp32 accumulators).
#define TN 64
#define TK 256
#define BKC 32
__global__ __launch_bounds__(256, 3) void dist_kernel(
    const float* __restrict__ x, const float* __restrict__ eT,
    const float* __restrict__ esq,
    int* __restrict__ min_idx, int* __restrict__ flag_cnt,
    int* __restrict__ flag_list)
{
    __shared__ float xs[BKC][TN];   // 8 KB
    __shared__ float es[BKC][TK];   // 32 KB

    const int t  = threadIdx.x;
    const int tn = t >> 5;          // 0..7  pixel group
    const int tk = t & 31;          // 0..31 code group
    const int blk = blockIdx.x;     // 0..2047
    const int n0 = blk * TN;
    const int b  = n0 / HWIMG;      // blocks never straddle batch (64 | 4096)
    const int hw0 = n0 % HWIMG;
    const float* xbase = x + (size_t)b * CC * HWIMG + hw0;  // [c*HWIMG + p]

    float min1[8], min2[8];
    int   idx1[8];
    #pragma unroll
    for (int i = 0; i < 8; i++) { min1[i] = 3.4e38f; min2[i] = 3.4e38f; idx1[i] = 0; }

    for (int kt = 0; kt < KCODES; kt += TK) {
        float acc[8][8];
        #pragma unroll
        for (int i = 0; i < 8; i++)
            #pragma unroll
            for (int j = 0; j < 8; j++) acc[i][j] = 0.0f;

        for (int cc = 0; cc < CC; cc += BKC) {
            // stage xs[32][64]: 512 float4, 2 per thread, coalesced
            {
                int tcol = t & 15, trow = t >> 4;   // trow 0..15
                #pragma unroll
                for (int i = 0; i < 2; i++) {
                    int c = trow + i * 16;
                    *(float4*)&xs[c][tcol * 4] =
                        *(const float4*)&xbase[(size_t)(cc + c) * HWIMG + tcol * 4];
                }
            }
            // stage es[32][256]: 2048 float4, 8 per thread, coalesced (uses eT)
            {
                int tcol = t & 63, trow = t >> 6;   // trow 0..3
                #pragma unroll
                for (int i = 0; i < 8; i++) {
                    int c = trow + i * 4;
                    *(float4*)&es[c][tcol * 4] =
                        *(const float4*)&eT[(size_t)(cc + c) * KCODES + kt + tcol * 4];
                }
            }
            __syncthreads();
            #pragma unroll 4
            for (int c = 0; c < BKC; c++) {
                float4 xa = *(const float4*)&xs[c][tn * 8];
                float4 xb = *(const float4*)&xs[c][tn * 8 + 4];
                float4 ea = *(const float4*)&es[c][tk * 8];
                float4 eb = *(const float4*)&es[c][tk * 8 + 4];
                float xv[8] = {xa.x, xa.y, xa.z, xa.w, xb.x, xb.y, xb.z, xb.w};
                float ev[8] = {ea.x, ea.y, ea.z, ea.w, eb.x, eb.y, eb.z, eb.w};
                #pragma unroll
                for (int i = 0; i < 8; i++)
                    #pragma unroll
                    for (int j = 0; j < 8; j++)
                        acc[i][j] = fmaf(xv[i], ev[j], acc[i][j]);
            }
            __syncthreads();
        }
        // distances for this k-pass; update running top-2 per pixel
        #pragma unroll
        for (int j = 0; j < 8; j++) {
            int kg = kt + tk * 8 + j;
            float eq = esq[kg];
            #pragma unroll
            for (int i = 0; i < 8; i++) {
                float d = fmaf(-2.0f, acc[i][j], eq);   // x^2 term constant per pixel
                if (d < min1[i]) { min2[i] = min1[i]; min1[i] = d; idx1[i] = kg; }
                else if (d < min2[i]) { min2[i] = d; }
            }
        }
    }

    // reduce (min1, idx1, min2) across the 32 tk-lanes (within half-wave)
    #pragma unroll
    for (int i = 0; i < 8; i++) {
        float m1 = min1[i]; int i1 = idx1[i]; float m2 = min2[i];
        #pragma unroll
        for (int m = 16; m; m >>= 1) {
            float o1 = __shfl_xor(m1, m, 64);
            int   oi = __shfl_xor(i1, m, 64);
            float o2 = __shfl_xor(m2, m, 64);
            if (o1 < m1 || (o1 == m1 && oi < i1)) {
                m2 = fminf(fminf(m2, o2), m1);
                m1 = o1; i1 = oi;
            } else {
                m2 = fminf(fminf(m2, o2), o1);
            }
        }
        if (tk == 0) {
            int n = n0 + tn * 8 + i;
            min_idx[n] = i1;
            if (m2 - m1 <= MARGIN) {            // near-tie: needs exact recheck
                int slot = atomicAdd(flag_cnt, 1);
                if (slot < MAXFLAG) flag_list[slot] = n;
            }
        }
    }
}

// ---------------- Kernel C: fp64 exact argmin for flagged pixels -------------
__global__ __launch_bounds__(256) void recheck_kernel(
    const float* __restrict__ x, const float* __restrict__ cb,
    const int* __restrict__ flag_cnt, const int* __restrict__ flag_list,
    int* __restrict__ min_idx)
{
    __shared__ float xv[CC];
    __shared__ double rv[256];
    __shared__ int    ri[256];
    int cnt = *flag_cnt; if (cnt > MAXFLAG) cnt = MAXFLAG;
    for (int f = blockIdx.x; f < cnt; f += gridDim.x) {
        int n = flag_list[f];
        int b = n / HWIMG, hw = n % HWIMG;
        const float* xb = x + (size_t)b * CC * HWIMG + hw;
        for (int c = threadIdx.x; c < CC; c += 256) xv[c] = xb[(size_t)c * HWIMG];
        __syncthreads();
        double best = 1e300; int bidx = KCODES;
        #pragma unroll
        for (int kk = 0; kk < 4; kk++) {
            int k = threadIdx.x * 4 + kk;
            const float* er = cb + (size_t)k * CC;
            double s = 0.0;
            for (int c = 0; c < CC; c++) {
                double diff = (double)xv[c] - (double)er[c];
                s = fma(diff, diff, s);
            }
            if (s < best) { best = s; bidx = k; }
        }
        rv[threadIdx.x] = best; ri[threadIdx.x] = bidx;
        __syncthreads();
        for (int s2 = 128; s2; s2 >>= 1) {
            if (threadIdx.x < (unsigned)s2) {
                double ov = rv[threadIdx.x + s2]; int oi = ri[threadIdx.x + s2];
                if (ov < rv[threadIdx.x] ||
                    (ov == rv[threadIdx.x] && oi < ri[threadIdx.x])) {
                    rv[threadIdx.x] = ov; ri[threadIdx.x] = oi;
                }
            }
            __syncthreads();
        }
        if (threadIdx.x == 0) min_idx[n] = ri[0];
        __syncthreads();
    }
}

// ---------------- Kernel D: gather output (NCHW) + loss partial sums ---------
__global__ __launch_bounds__(256) void out_kernel(
    const float* __restrict__ x, const float* __restrict__ cb,
    const int* __restrict__ min_idx, float* __restrict__ out,
    double* __restrict__ partials)
{
    int n = blockIdx.x * 256 + threadIdx.x;
    int b = n / HWIMG, hw = n % HWIMG;
    const float* xb = x + (size_t)b * CC * HWIMG + hw;
    float*       ob = out + (size_t)b * CC * HWIMG + hw;
    int k = min_idx[n];
    const float* er = cb + (size_t)k * CC;
    double ls = 0.0;
    #pragma unroll 4
    for (int c = 0; c < CC; c += 4) {
        float4 q = *(const float4*)&er[c];
        float x0 = xb[(size_t)(c + 0) * HWIMG];
        float x1 = xb[(size_t)(c + 1) * HWIMG];
        float x2 = xb[(size_t)(c + 2) * HWIMG];
        float x3 = xb[(size_t)(c + 3) * HWIMG];
        ob[(size_t)(c + 0) * HWIMG] = q.x;
        ob[(size_t)(c + 1) * HWIMG] = q.y;
        ob[(size_t)(c + 2) * HWIMG] = q.z;
        ob[(size_t)(c + 3) * HWIMG] = q.w;
        double d0 = (double)q.x - (double)x0;
        double d1 = (double)q.y - (double)x1;
        double d2 = (double)q.z - (double)x2;
        double d3 = (double)q.w - (double)x3;
        ls += d0 * d0 + d1 * d1 + d2 * d2 + d3 * d3;
    }
    __shared__ double sred[256];
    sred[threadIdx.x] = ls;
    __syncthreads();
    for (int s = 128; s; s >>= 1) {
        if (threadIdx.x < (unsigned)s) sred[threadIdx.x] += sred[threadIdx.x + s];
        __syncthreads();
    }
    if (threadIdx.x == 0) partials[blockIdx.x] = sred[0];
}

// ---------------- Kernel E: finalize loss ------------------------------------
__global__ void loss_kernel(const double* __restrict__ partials, float* __restrict__ out)
{
    if (threadIdx.x == 0 && blockIdx.x == 0) {
        double s = 0.0;
        for (int i = 0; i < 512; i++) s += partials[i];
        out[33554432] = (float)(1.25 * s / 33554432.0);
    }
}

// ---------------- Launch -----------------------------------------------------
extern "C" void kernel_launch(void* const* d_in, const int* in_sizes, int n_in,
                              void* d_out, int out_size, void* d_ws, size_t ws_size,
                              hipStream_t stream)
{
    const float* x  = (const float*)d_in[0];
    const float* cb = (const float*)d_in[1];
    float* out = (float*)d_out;

    char* ws = (char*)d_ws;
    float*  eT        = (float*)(ws + 0);            // 1,048,576 B
    float*  esq       = (float*)(ws + 1048576);      // 4,096 B
    int*    min_idx   = (int*)  (ws + 1052672);      // 524,288 B
    int*    flag_cnt  = (int*)  (ws + 1576960);      // 16 B
    int*    flag_list = (int*)  (ws + 1576976);      // 262,144 B
    double* partials  = (double*)(ws + 1839120);     // 4,096 B

    prep_kernel   <<<KCODES, 256, 0, stream>>>(cb, eT, esq, flag_cnt);
    dist_kernel   <<<NPIX / TN, 256, 0, stream>>>(x, eT, esq, min_idx, flag_cnt, flag_list);
    recheck_kernel<<<256, 256, 0, stream>>>(x, cb, flag_cnt, flag_list, min_idx);
    out_kernel    <<<NPIX / 256, 256, 0, stream>>>(x, cb, min_idx, out, partials);
    loss_kernel   <<<1, 64, 0, stream>>>(partials, out);
}

// Round 3
// 773.798 us; speedup vs baseline: 1.1932x; 1.1932x over previous
//
#include <hip/hip_runtime.h>

#define CC 256
#define HWIMG 4096
#define NPIX 131072
#define KCODES 1024
#define MAXFLAG 65536
#define MARGIN 0.03125f

typedef short short8v __attribute__((ext_vector_type(8)));
typedef float f32x4 __attribute__((ext_vector_type(4)));
typedef unsigned short u16;

__device__ __forceinline__ void bf16split(float v, u16& hi, u16& lo) {
    unsigned u = __float_as_uint(v);
    unsigned r = u + 0x7FFF + ((u >> 16) & 1);     // RNE to bf16
    hi = (u16)(r >> 16);
    float hf = __uint_as_float((unsigned)hi << 16);
    float l = v - hf;                               // exact
    unsigned u2 = __float_as_uint(l);
    unsigned r2 = u2 + 0x7FFF + ((u2 >> 16) & 1);
    lo = (u16)(r2 >> 16);
}

// ---------- prep_e: codebook -> bf16 hi/lo + esq; zero flag counter ----------
__global__ __launch_bounds__(256) void prep_e(const float* __restrict__ cb,
    u16* __restrict__ e_hi, u16* __restrict__ e_lo,
    float* __restrict__ esq, int* __restrict__ flag_cnt)
{
    int k = blockIdx.x, c = threadIdx.x;
    float v = cb[(size_t)k * CC + c];
    u16 hi, lo; bf16split(v, hi, lo);
    e_hi[(size_t)k * CC + c] = hi;
    e_lo[(size_t)k * CC + c] = lo;
    float s = v * v;
    #pragma unroll
    for (int m = 32; m; m >>= 1) s += __shfl_xor(s, m, 64);
    __shared__ float red[4];
    if ((c & 63) == 0) red[c >> 6] = s;
    __syncthreads();
    if (c == 0) {
        esq[k] = (red[0] + red[1]) + (red[2] + red[3]);
        if (k == 0) *flag_cnt = 0;
    }
}

// ---------- prep_xT: x NCHW fp32 -> xT[n][c] bf16 hi/lo (stored in d_out) ----
__global__ __launch_bounds__(256) void prep_xT(const float* __restrict__ x,
    u16* __restrict__ xt_hi, u16* __restrict__ xt_lo)
{
    __shared__ unsigned pk[64 * 261];
    const int blk = blockIdx.x, t = threadIdx.x;
    const float* xb = x + (size_t)(blk >> 6) * (CC * HWIMG) + (blk & 63) * 64;
    #pragma unroll 4
    for (int p = 0; p < 16; ++p) {
        int c = p * 16 + (t >> 4);
        int px4 = (t & 15) * 4;
        float4 v = *(const float4*)&xb[(size_t)c * HWIMG + px4];
        float vv[4] = {v.x, v.y, v.z, v.w};
        #pragma unroll
        for (int i = 0; i < 4; ++i) {
            u16 hi, lo; bf16split(vv[i], hi, lo);
            pk[(px4 + i) * 261 + c] = ((unsigned)hi << 16) | lo;
        }
    }
    __syncthreads();
    const int px = t & 63, c0 = (t >> 6) * 64;
    size_t row = (size_t)(blk * 64 + px) * CC + c0;
    for (int j8 = 0; j8 < 8; ++j8) {
        short8v hv, lv;
        #pragma unroll
        for (int j = 0; j < 8; ++j) {
            unsigned w = pk[px * 261 + c0 + j8 * 8 + j];
            hv[j] = (short)(w >> 16);
            lv[j] = (short)(w & 0xFFFF);
        }
        *(short8v*)&xt_hi[row + j8 * 8] = hv;
        *(short8v*)&xt_lo[row + j8 * 8] = lv;
    }
}

// ---------- dist: 3-term bf16-split MFMA distance + top-2 argmin -------------
// Block 256 thr = 4 waves (code-split). Tile: 64 px (block) x 256 codes (pass).
// Wave: 64px x 64codes = 4m x 4n frags of mfma_f32_16x16x32_bf16.
__global__ __launch_bounds__(256, 2) void dist_kernel(
    const u16* __restrict__ xt_hi, const u16* __restrict__ xt_lo,
    const u16* __restrict__ e_hi, const u16* __restrict__ e_lo,
    const float* __restrict__ esq,
    int* __restrict__ min_idx, int* __restrict__ flag_cnt,
    int* __restrict__ flag_list)
{
    __shared__ char smem[81920];   // xh 8K | xl 8K | eh 32K | el 32K
    char* xhp = smem;
    char* xlp = smem + 8192;
    char* ehp = smem + 16384;
    char* elp = smem + 49152;

    const int t = threadIdx.x;
    const int l = t & 63;
    const int wid = t >> 6;          // 0..3, code sub-range
    const int n0 = blockIdx.x * 64;  // pixel base

    const int lrow = l & 15;
    const int lk   = (l >> 4) * 16;  // 16B slot for k-group
    const int lx   = (l & 7) << 4;   // XOR swizzle mask (row&7 == l&7)

    float min1[16], min2[16]; int idx1[16];
    #pragma unroll
    for (int s = 0; s < 16; ++s) { min1[s] = 3.4e38f; min2[s] = 3.4e38f; idx1[s] = 0; }

    for (int pass = 0; pass < 4; ++pass) {
        const int ct0 = pass * 256;
        f32x4 acc[4][4];
        #pragma unroll
        for (int m = 0; m < 4; ++m)
            #pragma unroll
            for (int n = 0; n < 4; ++n) acc[m][n] = (f32x4){0.f, 0.f, 0.f, 0.f};

        for (int ks = 0; ks < 4; ++ks) {
            const int k0 = ks * 64;
            // stage x chunk: 64px x 64c (hi+lo), 2 chunks/thread/array
            #pragma unroll
            for (int i = 0; i < 2; ++i) {
                int id = t + 256 * i;
                int px = id >> 3, c8 = id & 7;
                size_t g = (size_t)(n0 + px) * CC + k0 + c8 * 8;
                int wb = (px * 128 + c8 * 16) ^ ((px & 7) << 4);
                *(short8v*)(xhp + wb) = *(const short8v*)&xt_hi[g];
                *(short8v*)(xlp + wb) = *(const short8v*)&xt_lo[g];
            }
            // stage e chunk: 256codes x 64c (hi+lo), 8 chunks/thread/array
            #pragma unroll
            for (int i = 0; i < 8; ++i) {
                int id = t + 256 * i;
                int code = id >> 3, c8 = id & 7;
                size_t g = (size_t)(ct0 + code) * CC + k0 + c8 * 8;
                int wb = (code * 128 + c8 * 16) ^ ((code & 7) << 4);
                *(short8v*)(ehp + wb) = *(const short8v*)&e_hi[g];
                *(short8v*)(elp + wb) = *(const short8v*)&e_lo[g];
            }
            __syncthreads();
            #pragma unroll
            for (int sub = 0; sub < 2; ++sub) {
                short8v Bh[4], Bl[4];
                #pragma unroll
                for (int n = 0; n < 4; ++n) {
                    int raw = (wid * 64 + n * 16 + lrow) * 128 + sub * 64 + lk;
                    Bh[n] = *(const short8v*)(ehp + (raw ^ lx));
                    Bl[n] = *(const short8v*)(elp + (raw ^ lx));
                }
                #pragma unroll
                for (int m = 0; m < 4; ++m) {
                    int raw = (m * 16 + lrow) * 128 + sub * 64 + lk;
                    short8v Ah = *(const short8v*)(xhp + (raw ^ lx));
                    short8v Al = *(const short8v*)(xlp + (raw ^ lx));
                    #pragma unroll
                    for (int n = 0; n < 4; ++n) {
                        acc[m][n] = __builtin_amdgcn_mfma_f32_16x16x32_bf16(Ah, Bh[n], acc[m][n], 0, 0, 0);
                        acc[m][n] = __builtin_amdgcn_mfma_f32_16x16x32_bf16(Al, Bh[n], acc[m][n], 0, 0, 0);
                        acc[m][n] = __builtin_amdgcn_mfma_f32_16x16x32_bf16(Ah, Bl[n], acc[m][n], 0, 0, 0);
                    }
                }
            }
            __syncthreads();
        }
        // epilogue: d = esq - 2*dot; running top-2 per (m,reg)
        #pragma unroll
        for (int n = 0; n < 4; ++n) {
            int code = ct0 + wid * 64 + n * 16 + lrow;
            float eq = esq[code];
            #pragma unroll
            for (int m = 0; m < 4; ++m) {
                #pragma unroll
                for (int r = 0; r < 4; ++r) {
                    float d = fmaf(-2.0f, acc[m][n][r], eq);
                    int s = m * 4 + r;
                    if (d < min1[s]) { min2[s] = min1[s]; min1[s] = d; idx1[s] = code; }
                    else if (d < min2[s]) { min2[s] = d; }
                }
            }
        }
    }

    // reduce over the 16 lrow lanes (codes within wave)
    float* rm1 = (float*)smem;
    float* rm2 = (float*)(smem + 1024);
    int*   rim = (int*)(smem + 2048);
    #pragma unroll
    for (int s = 0; s < 16; ++s) {
        float m1 = min1[s]; int i1 = idx1[s]; float m2 = min2[s];
        #pragma unroll
        for (int msk = 1; msk <= 8; msk <<= 1) {
            float o1 = __shfl_xor(m1, msk, 64);
            int   oi = __shfl_xor(i1, msk, 64);
            float o2 = __shfl_xor(m2, msk, 64);
            if (o1 < m1 || (o1 == m1 && oi < i1)) { m2 = fminf(fminf(m2, o2), m1); m1 = o1; i1 = oi; }
            else { m2 = fminf(fminf(m2, o2), o1); }
        }
        if (lrow == 0) {
            int px_local = (s >> 2) * 16 + (l >> 4) * 4 + (s & 3);
            rm1[wid * 64 + px_local] = m1;
            rm2[wid * 64 + px_local] = m2;
            rim[wid * 64 + px_local] = i1;
        }
    }
    __syncthreads();
    // merge the 4 waves (code quarters) per pixel
    if (t < 64) {
        float m1 = rm1[t]; int i1 = rim[t]; float m2 = rm2[t];
        #pragma unroll
        for (int w = 1; w < 4; ++w) {
            float o1 = rm1[w * 64 + t]; int oi = rim[w * 64 + t]; float o2 = rm2[w * 64 + t];
            if (o1 < m1 || (o1 == m1 && oi < i1)) { m2 = fminf(fminf(m2, o2), m1); m1 = o1; i1 = oi; }
            else { m2 = fminf(fminf(m2, o2), o1); }
        }
        min_idx[n0 + t] = i1;
        if (m2 - m1 <= MARGIN) {
            int slot = atomicAdd(flag_cnt, 1);
            if (slot < MAXFLAG) flag_list[slot] = n0 + t;
        }
    }
}

// ---------- recheck: fp64 exact argmin for flagged pixels --------------------
__global__ __launch_bounds__(256) void recheck_kernel(
    const float* __restrict__ x, const float* __restrict__ cb,
    const int* __restrict__ flag_cnt, const int* __restrict__ flag_list,
    int* __restrict__ min_idx)
{
    __shared__ float xv[CC];
    __shared__ double rv[256];
    __shared__ int    ri[256];
    int cnt = *flag_cnt; if (cnt > MAXFLAG) cnt = MAXFLAG;
    for (int f = blockIdx.x; f < cnt; f += gridDim.x) {
        int n = flag_list[f];
        int b = n / HWIMG, hw = n % HWIMG;
        const float* xb = x + (size_t)b * CC * HWIMG + hw;
        for (int c = threadIdx.x; c < CC; c += 256) xv[c] = xb[(size_t)c * HWIMG];
        __syncthreads();
        double best = 1e300; int bidx = KCODES;
        #pragma unroll
        for (int kk = 0; kk < 4; kk++) {
            int k = threadIdx.x * 4 + kk;
            const float* er = cb + (size_t)k * CC;
            double s = 0.0;
            for (int c = 0; c < CC; c++) {
                double diff = (double)xv[c] - (double)er[c];
                s = fma(diff, diff, s);
            }
            if (s < best) { best = s; bidx = k; }
        }
        rv[threadIdx.x] = best; ri[threadIdx.x] = bidx;
        __syncthreads();
        for (int s2 = 128; s2; s2 >>= 1) {
            if (threadIdx.x < (unsigned)s2) {
                double ov = rv[threadIdx.x + s2]; int oi = ri[threadIdx.x + s2];
                if (ov < rv[threadIdx.x] ||
                    (ov == rv[threadIdx.x] && oi < ri[threadIdx.x])) {
                    rv[threadIdx.x] = ov; ri[threadIdx.x] = oi;
                }
            }
            __syncthreads();
        }
        if (threadIdx.x == 0) min_idx[n] = ri[0];
        __syncthreads();
    }
}

// ---------- out: gather quantized (NCHW) + fp64 loss partials ----------------
__global__ __launch_bounds__(256) void out_kernel(
    const float* __restrict__ x, const float* __restrict__ cb,
    const int* __restrict__ min_idx, float* __restrict__ out,
    double* __restrict__ partials)
{
    int n = blockIdx.x * 256 + threadIdx.x;
    int b = n / HWIMG, hw = n % HWIMG;
    const float* xb = x + (size_t)b * CC * HWIMG + hw;
    float*       ob = out + (size_t)b * CC * HWIMG + hw;
    int k = min_idx[n];
    const float* er = cb + (size_t)k * CC;
    double ls = 0.0;
    #pragma unroll 4
    for (int c = 0; c < CC; c += 4) {
        float4 q = *(const float4*)&er[c];
        float x0 = xb[(size_t)(c + 0) * HWIMG];
        float x1 = xb[(size_t)(c + 1) * HWIMG];
        float x2 = xb[(size_t)(c + 2) * HWIMG];
        float x3 = xb[(size_t)(c + 3) * HWIMG];
        ob[(size_t)(c + 0) * HWIMG] = q.x;
        ob[(size_t)(c + 1) * HWIMG] = q.y;
        ob[(size_t)(c + 2) * HWIMG] = q.z;
        ob[(size_t)(c + 3) * HWIMG] = q.w;
        double d0 = (double)q.x - (double)x0;
        double d1 = (double)q.y - (double)x1;
        double d2 = (double)q.z - (double)x2;
        double d3 = (double)q.w - (double)x3;
        ls += d0 * d0 + d1 * d1 + d2 * d2 + d3 * d3;
    }
    __shared__ double sred[256];
    sred[threadIdx.x] = ls;
    __syncthreads();
    for (int s = 128; s; s >>= 1) {
        if (threadIdx.x < (unsigned)s) sred[threadIdx.x] += sred[threadIdx.x + s];
        __syncthreads();
    }
    if (threadIdx.x == 0) partials[blockIdx.x] = sred[0];
}

__global__ void loss_kernel(const double* __restrict__ partials, float* __restrict__ out)
{
    if (threadIdx.x == 0 && blockIdx.x == 0) {
        double s = 0.0;
        for (int i = 0; i < 512; i++) s += partials[i];
        out[33554432] = (float)(1.25 * s / 33554432.0);
    }
}

// ---------- launch -----------------------------------------------------------
extern "C" void kernel_launch(void* const* d_in, const int* in_sizes, int n_in,
                              void* d_out, int out_size, void* d_ws, size_t ws_size,
                              hipStream_t stream)
{
    const float* x  = (const float*)d_in[0];
    const float* cb = (const float*)d_in[1];
    float* out = (float*)d_out;

    // xT scratch lives in d_out (134,217,728 B <= out bytes); out_kernel
    // rewrites d_out afterwards, reading only x/cb/min_idx.
    u16* xt_hi = (u16*)d_out;
    u16* xt_lo = xt_hi + (size_t)NPIX * CC;

    char* ws = (char*)d_ws;
    u16*    e_hi      = (u16*)  (ws + 0);            // 524,288 B
    u16*    e_lo      = (u16*)  (ws + 524288);       // 524,288 B
    float*  esq       = (float*)(ws + 1048576);      // 4,096 B
    int*    min_idx   = (int*)  (ws + 1052672);      // 524,288 B
    int*    flag_cnt  = (int*)  (ws + 1576960);      // 16 B
    int*    flag_list = (int*)  (ws + 1576976);      // 262,144 B
    double* partials  = (double*)(ws + 1839120);     // 4,096 B

    prep_e        <<<KCODES, 256, 0, stream>>>(cb, e_hi, e_lo, esq, flag_cnt);
    prep_xT       <<<NPIX / 64, 256, 0, stream>>>(x, xt_hi, xt_lo);
    dist_kernel   <<<NPIX / 64, 256, 0, stream>>>(xt_hi, xt_lo, e_hi, e_lo, esq,
                                                  min_idx, flag_cnt, flag_list);
    recheck_kernel<<<256, 256, 0, stream>>>(x, cb, flag_cnt, flag_list, min_idx);
    out_kernel    <<<NPIX / 256, 256, 0, stream>>>(x, cb, min_idx, out, partials);
    loss_kernel   <<<1, 64, 0, stream>>>(partials, out);
}

// Round 4
// 538.249 us; speedup vs baseline: 1.7154x; 1.4376x over previous
//
#include <hip/hip_runtime.h>
#include <hip/hip_fp16.h>

#define CC 256
#define HWIMG 4096
#define NPIX 131072
#define KCODES 1024
#define MAXFLAG 65536
#define MARGIN 0.125f

typedef _Float16 half8 __attribute__((ext_vector_type(8)));
typedef short short8v __attribute__((ext_vector_type(8)));
typedef float f32x4 __attribute__((ext_vector_type(4)));
typedef unsigned short u16;
typedef unsigned int u32;

__device__ __forceinline__ void gld16(const void* g, void* l) {
    __builtin_amdgcn_global_load_lds(
        (const __attribute__((address_space(1))) void*)g,
        (__attribute__((address_space(3))) void*)l, 16, 0, 0);
}

// ---------- prep_e: codebook -> fp16 pre-swizzled chunk images + esq ---------
// e_prep layout: [pass 4][ks 4] 32 KB images; image byte o holds fp16 of
// e[pass*256 + row][ks*64 + cidx] where o' = o ^ ((row&7)<<4), row = o>>7,
// cidx = (o'&127)>>1.  (So linear global_load_lds + XOR-swizzled ds_read work.)
__global__ __launch_bounds__(256) void prep_e(const float* __restrict__ cb,
    u16* __restrict__ e_prep, float* __restrict__ esq, int* __restrict__ flag_cnt)
{
    __shared__ u16 eh[256];
    __shared__ float red[4];
    int k = blockIdx.x, c = threadIdx.x;
    float v = cb[(size_t)k * CC + c];
    eh[c] = __half_as_ushort(__float2half(v));
    float s = v * v;
    #pragma unroll
    for (int m = 32; m; m >>= 1) s += __shfl_xor(s, m, 64);
    if ((c & 63) == 0) red[c >> 6] = s;
    __syncthreads();
    if (c == 0) {
        esq[k] = (red[0] + red[1]) + (red[2] + red[3]);
        if (k == 0) *flag_cnt = 0;
    }
    if (c < 32) {
        int ks = c >> 3, cg = c & 7;
        int pass = k >> 8, row = k & 255;
        int o = (row * 128 + cg * 16) ^ ((row & 7) << 4);
        short8v w;
        #pragma unroll
        for (int j = 0; j < 8; ++j) w[j] = (short)eh[ks * 64 + cg * 8 + j];
        *(short8v*)((char*)e_prep + (size_t)(pass * 4 + ks) * 32768 + o) = w;
    }
}

// ---------- prep_xT: x NCHW fp32 -> fp16 hi/lo pre-swizzled chunks (d_out) ---
// x_prep layout: [dblk 2048][ks 4][xh 8 KB | xl 8 KB]; same swizzle rule as e.
__global__ __launch_bounds__(256) void prep_xT(const float* __restrict__ x,
    char* __restrict__ x_prep)
{
    __shared__ u32 pk[64 * 260];      // [px][c] packed (hi<<16)|lo
    const int blk = blockIdx.x, t = threadIdx.x;
    const float* xb = x + (size_t)(blk >> 6) * (CC * HWIMG) + (blk & 63) * 64;
    #pragma unroll 4
    for (int p = 0; p < 16; ++p) {
        int c = p * 16 + (t >> 4);
        int px4 = (t & 15) * 4;
        float4 v = *(const float4*)&xb[(size_t)c * HWIMG + px4];
        float vv[4] = {v.x, v.y, v.z, v.w};
        #pragma unroll
        for (int i = 0; i < 4; ++i) {
            __half h = __float2half(vv[i]);
            __half lo = __float2half(vv[i] - __half2float(h));
            pk[(px4 + i) * 260 + c] =
                ((u32)__half_as_ushort(h) << 16) | __half_as_ushort(lo);
        }
    }
    __syncthreads();
    char* obase = x_prep + (size_t)blk * 65536;
    #pragma unroll
    for (int i = 0; i < 16; ++i) {
        int gid = t + 256 * i;            // [ks 4][h 2][g 512]
        int ks = gid >> 10, rem = gid & 1023, h = rem >> 9, g = rem & 511;
        int row = g >> 3;
        int cg = (g & 7) ^ (row & 7);     // logical c-granule after swizzle
        int c0 = ks * 64 + cg * 8;
        const u32* pr = &pk[row * 260 + c0];
        uint4 a = *(const uint4*)pr;
        uint4 b = *(const uint4*)(pr + 4);
        u32 w[8] = {a.x, a.y, a.z, a.w, b.x, b.y, b.z, b.w};
        short8v ov;
        #pragma unroll
        for (int j = 0; j < 8; ++j)
            ov[j] = h ? (short)(w[j] & 0xFFFF) : (short)(w[j] >> 16);
        *(short8v*)(obase + (size_t)ks * 16384 + h * 8192 + g * 16) = ov;
    }
}

// ---------- dist: 2-term fp16 MFMA distance + top-2 argmin -------------------
// 256 thr = 4 waves (code quarters). Tile 64 px x 256 codes/pass, 4 passes.
// Per chunk (64 c): LDS = xh 8K | xl 8K | eh 32K = 48 KB, global_load_lds.
__global__ __launch_bounds__(256, 3) void dist_kernel(
    const char* __restrict__ x_prep, const char* __restrict__ e_prep,
    const float* __restrict__ esq,
    int* __restrict__ min_idx, int* __restrict__ flag_cnt,
    int* __restrict__ flag_list)
{
    __shared__ char smem[49152];
    char* xhp = smem;
    char* xlp = smem + 8192;
    char* ehp = smem + 16384;

    const int t = threadIdx.x;
    const int l = t & 63;
    const int wid = t >> 6;
    const int n0 = blockIdx.x * 64;

    const int lrow = l & 15;
    const int lk   = (l >> 4) * 16;
    const int lx   = (l & 7) << 4;

    const char* xsrc = x_prep + (size_t)blockIdx.x * 65536;

    float min1[16], min2[16]; int idx1[16];
    #pragma unroll
    for (int s = 0; s < 16; ++s) { min1[s] = 3.4e38f; min2[s] = 3.4e38f; idx1[s] = 0; }

    f32x4 acc[4][4];

    for (int r = 0; r < 16; ++r) {
        const int pass = r >> 2, ks = r & 3;
        // stage chunk r (linear dest; swizzle pre-baked in global layout)
        {
            const char* xs = xsrc + ks * 16384;
            const char* es = e_prep + r * 32768;
            #pragma unroll
            for (int i = 0; i < 4; ++i)
                gld16(xs + wid * 4096 + i * 1024 + l * 16,
                      smem + wid * 4096 + i * 1024);
            #pragma unroll
            for (int i = 0; i < 8; ++i)
                gld16(es + wid * 8192 + i * 1024 + l * 16,
                      ehp + wid * 8192 + i * 1024);
        }
        asm volatile("s_waitcnt vmcnt(0)" ::: "memory");
        __syncthreads();

        if (ks == 0) {
            #pragma unroll
            for (int m = 0; m < 4; ++m)
                #pragma unroll
                for (int n = 0; n < 4; ++n) acc[m][n] = (f32x4){0.f, 0.f, 0.f, 0.f};
        }
        #pragma unroll
        for (int sub = 0; sub < 2; ++sub) {
            half8 B[4];
            #pragma unroll
            for (int n = 0; n < 4; ++n) {
                int raw = (wid * 64 + n * 16 + lrow) * 128 + sub * 64 + lk;
                B[n] = *(const half8*)(ehp + (raw ^ lx));
            }
            #pragma unroll
            for (int m = 0; m < 4; ++m) {
                int raw = (m * 16 + lrow) * 128 + sub * 64 + lk;
                half8 Ah = *(const half8*)(xhp + (raw ^ lx));
                half8 Al = *(const half8*)(xlp + (raw ^ lx));
                #pragma unroll
                for (int n = 0; n < 4; ++n) {
                    acc[m][n] = __builtin_amdgcn_mfma_f32_16x16x32_f16(Ah, B[n], acc[m][n], 0, 0, 0);
                    acc[m][n] = __builtin_amdgcn_mfma_f32_16x16x32_f16(Al, B[n], acc[m][n], 0, 0, 0);
                }
            }
        }
        if (ks == 3) {   // pass epilogue: d = esq - 2*dot, top-2 update
            #pragma unroll
            for (int n = 0; n < 4; ++n) {
                int code = pass * 256 + wid * 64 + n * 16 + lrow;
                float eq = esq[code];
                #pragma unroll
                for (int m = 0; m < 4; ++m) {
                    #pragma unroll
                    for (int q = 0; q < 4; ++q) {
                        float d = fmaf(-2.0f, acc[m][n][q], eq);
                        int s = m * 4 + q;
                        if (d < min1[s]) { min2[s] = min1[s]; min1[s] = d; idx1[s] = code; }
                        else if (d < min2[s]) { min2[s] = d; }
                    }
                }
            }
        }
        __syncthreads();
    }

    // reduce across 16 code-lanes, then across the 4 waves
    float* rm1 = (float*)smem;
    float* rm2 = (float*)(smem + 1024);
    int*   rim = (int*)(smem + 2048);
    #pragma unroll
    for (int s = 0; s < 16; ++s) {
        float m1 = min1[s]; int i1 = idx1[s]; float m2 = min2[s];
        #pragma unroll
        for (int msk = 1; msk <= 8; msk <<= 1) {
            float o1 = __shfl_xor(m1, msk, 64);
            int   oi = __shfl_xor(i1, msk, 64);
            float o2 = __shfl_xor(m2, msk, 64);
            if (o1 < m1 || (o1 == m1 && oi < i1)) { m2 = fminf(fminf(m2, o2), m1); m1 = o1; i1 = oi; }
            else { m2 = fminf(fminf(m2, o2), o1); }
        }
        if (lrow == 0) {
            int px_local = (s >> 2) * 16 + (l >> 4) * 4 + (s & 3);
            rm1[wid * 64 + px_local] = m1;
            rm2[wid * 64 + px_local] = m2;
            rim[wid * 64 + px_local] = i1;
        }
    }
    __syncthreads();
    if (t < 64) {
        float m1 = rm1[t]; int i1 = rim[t]; float m2 = rm2[t];
        #pragma unroll
        for (int w = 1; w < 4; ++w) {
            float o1 = rm1[w * 64 + t]; int oi = rim[w * 64 + t]; float o2 = rm2[w * 64 + t];
            if (o1 < m1 || (o1 == m1 && oi < i1)) { m2 = fminf(fminf(m2, o2), m1); m1 = o1; i1 = oi; }
            else { m2 = fminf(fminf(m2, o2), o1); }
        }
        min_idx[n0 + t] = i1;
        if (m2 - m1 <= MARGIN) {
            int slot = atomicAdd(flag_cnt, 1);
            if (slot < MAXFLAG) flag_list[slot] = n0 + t;
        }
    }
}

// ---------- recheck: fp64 exact argmin for flagged pixels --------------------
__global__ __launch_bounds__(256) void recheck_kernel(
    const float* __restrict__ x, const float* __restrict__ cb,
    const int* __restrict__ flag_cnt, const int* __restrict__ flag_list,
    int* __restrict__ min_idx)
{
    __shared__ float xv[CC];
    __shared__ double rv[256];
    __shared__ int    ri[256];
    int cnt = *flag_cnt; if (cnt > MAXFLAG) cnt = MAXFLAG;
    for (int f = blockIdx.x; f < cnt; f += gridDim.x) {
        int n = flag_list[f];
        int b = n / HWIMG, hw = n % HWIMG;
        const float* xb = x + (size_t)b * CC * HWIMG + hw;
        for (int c = threadIdx.x; c < CC; c += 256) xv[c] = xb[(size_t)c * HWIMG];
        __syncthreads();
        double best = 1e300; int bidx = KCODES;
        #pragma unroll
        for (int kk = 0; kk < 4; kk++) {
            int k = threadIdx.x * 4 + kk;
            const float* er = cb + (size_t)k * CC;
            double s = 0.0;
            for (int c = 0; c < CC; c++) {
                double diff = (double)xv[c] - (double)er[c];
                s = fma(diff, diff, s);
            }
            if (s < best) { best = s; bidx = k; }
        }
        rv[threadIdx.x] = best; ri[threadIdx.x] = bidx;
        __syncthreads();
        for (int s2 = 128; s2; s2 >>= 1) {
            if (threadIdx.x < (unsigned)s2) {
                double ov = rv[threadIdx.x + s2]; int oi = ri[threadIdx.x + s2];
                if (ov < rv[threadIdx.x] ||
                    (ov == rv[threadIdx.x] && oi < ri[threadIdx.x])) {
                    rv[threadIdx.x] = ov; ri[threadIdx.x] = oi;
                }
            }
            __syncthreads();
        }
        if (threadIdx.x == 0) min_idx[n] = ri[0];
        __syncthreads();
    }
}

// ---------- out: gather quantized (NCHW) + fp64 loss partials ----------------
__global__ __launch_bounds__(256) void out_kernel(
    const float* __restrict__ x, const float* __restrict__ cb,
    const int* __restrict__ min_idx, float* __restrict__ out,
    double* __restrict__ partials)
{
    int n = blockIdx.x * 256 + threadIdx.x;
    int b = n / HWIMG, hw = n % HWIMG;
    const float* xb = x + (size_t)b * CC * HWIMG + hw;
    float*       ob = out + (size_t)b * CC * HWIMG + hw;
    int k = min_idx[n];
    const float* er = cb + (size_t)k * CC;
    double ls = 0.0;
    #pragma unroll 4
    for (int c = 0; c < CC; c += 4) {
        float4 q = *(const float4*)&er[c];
        float x0 = xb[(size_t)(c + 0) * HWIMG];
        float x1 = xb[(size_t)(c + 1) * HWIMG];
        float x2 = xb[(size_t)(c + 2) * HWIMG];
        float x3 = xb[(size_t)(c + 3) * HWIMG];
        ob[(size_t)(c + 0) * HWIMG] = q.x;
        ob[(size_t)(c + 1) * HWIMG] = q.y;
        ob[(size_t)(c + 2) * HWIMG] = q.z;
        ob[(size_t)(c + 3) * HWIMG] = q.w;
        double d0 = (double)q.x - (double)x0;
        double d1 = (double)q.y - (double)x1;
        double d2 = (double)q.z - (double)x2;
        double d3 = (double)q.w - (double)x3;
        ls += d0 * d0 + d1 * d1 + d2 * d2 + d3 * d3;
    }
    __shared__ double sred[256];
    sred[threadIdx.x] = ls;
    __syncthreads();
    for (int s = 128; s; s >>= 1) {
        if (threadIdx.x < (unsigned)s) sred[threadIdx.x] += sred[threadIdx.x + s];
        __syncthreads();
    }
    if (threadIdx.x == 0) partials[blockIdx.x] = sred[0];
}

__global__ void loss_kernel(const double* __restrict__ partials, float* __restrict__ out)
{
    if (threadIdx.x == 0 && blockIdx.x == 0) {
        double s = 0.0;
        for (int i = 0; i < 512; i++) s += partials[i];
        out[33554432] = (float)(1.25 * s / 33554432.0);
    }
}

// ---------- launch -----------------------------------------------------------
extern "C" void kernel_launch(void* const* d_in, const int* in_sizes, int n_in,
                              void* d_out, int out_size, void* d_ws, size_t ws_size,
                              hipStream_t stream)
{
    const float* x  = (const float*)d_in[0];
    const float* cb = (const float*)d_in[1];
    float* out = (float*)d_out;

    // x_prep (128 MB) lives in d_out; out_kernel rewrites d_out afterwards.
    char* x_prep = (char*)d_out;

    char* ws = (char*)d_ws;
    u16*    e_prep    = (u16*)  (ws + 0);            // 524,288 B
    float*  esq       = (float*)(ws + 524288);       // 4,096 B
    int*    min_idx   = (int*)  (ws + 528384);       // 524,288 B
    int*    flag_cnt  = (int*)  (ws + 1052672);      // 16 B
    int*    flag_list = (int*)  (ws + 1052688);      // 262,144 B
    double* partials  = (double*)(ws + 1314832);     // 4,096 B

    prep_e        <<<KCODES, 256, 0, stream>>>(cb, e_prep, esq, flag_cnt);
    prep_xT       <<<NPIX / 64, 256, 0, stream>>>(x, x_prep);
    dist_kernel   <<<NPIX / 64, 256, 0, stream>>>(x_prep, (const char*)e_prep, esq,
                                                  min_idx, flag_cnt, flag_list);
    recheck_kernel<<<256, 256, 0, stream>>>(x, cb, flag_cnt, flag_list, min_idx);
    out_kernel    <<<NPIX / 256, 256, 0, stream>>>(x, cb, min_idx, out, partials);
    loss_kernel   <<<1, 64, 0, stream>>>(partials, out);
}